// Round 9
// baseline (213.196 us; speedup 1.0000x reference)
//
#include <hip/hip_runtime.h>

#define D 16
#define WQT 4        // q-tiles (of 16 queries) per wave -> 64 queries/wave
#define NCHUNK 256   // n-dimension grid split; 8*256=2048 blocks = 8/CU = 32 waves/CU
#define TILES_MAX 25 // base=24 (+1 for the first `rem` chunks)

#define LOG2E 1.4426950408889634f
#define LN2   0.6931471805599453f

typedef __attribute__((ext_vector_type(8))) short bf16x8;
typedef __attribute__((ext_vector_type(4))) float f32x4;

__device__ __forceinline__ unsigned short f2bf(float f) {
    unsigned u = __float_as_uint(f);
    unsigned r = (u + 0x7fffu + ((u >> 16) & 1u)) >> 16;
    return (unsigned short)r;
}

// ---- fused convert + weight-sum + density partials + last-block finalize ----
// part[chunk][q] = sum_{n in chunk} exp2( L*(x_q.d_n) - 0.5*L*|d_n|^2 + log2 w_n )
// wpart[chunk]   = sum_{n in chunk} w_n   (idempotent across x-duplicates)
// The last y-block of each x-column finalizes that column's 256 queries.
__global__ __launch_bounds__(256, 8) void dens_kernel(
        const float* __restrict__ X, const float* __restrict__ data,
        const float* __restrict__ w, float* __restrict__ part,
        float* __restrict__ wpart, unsigned* __restrict__ cnt,
        float* __restrict__ out, int Q, int N) {
    // +1 tile pad so the depth-1 prefetch can read one-past-end harmlessly
    __shared__ unsigned short sh_hi[(TILES_MAX + 1) * 256];  // 13.3 KB
    __shared__ float          sh_cn[(TILES_MAX + 1) * 16];   // 1.7 KB
    __shared__ float          ls[4];
    __shared__ float          swsum;
    __shared__ int            amLast;

    const int tid  = threadIdx.x;
    const int lane = tid & 63;
    const int wave = tid >> 6;
    const int col  = lane & 15;        // A: m-index; C/D: n-index
    const int quad = lane >> 4;
    const int koff = (quad & 1) * 8;   // k-slice within D=16

    const int g  = blockIdx.x;         // x-column: 256 queries
    const int qg = g * 4 + wave;       // wave q-group: 64 queries

    // ---- this block's n-tile range (tiles of 16 points)
    const int NT = N >> 4;                       // 6250
    const int base = NT / NCHUNK, rem = NT % NCHUNK;
    const int chunk = blockIdx.y;
    const int tile0 = chunk * base + min(chunk, rem);
    const int cntt = base + (chunk < rem ? 1 : 0);
    const int npts = cntt * 16;
    const int n0 = tile0 * 16;

    // ---- stage: fp32 -> bf16 pack + per-point constant into LDS; weight sum aside
    float wsl = 0.f;
    for (int p = tid; p < npts; p += 256) {
        const float4* dp = (const float4*)(data + (size_t)(n0 + p) * D);
        float4 v0 = dp[0], v1 = dp[1], v2 = dp[2], v3 = dp[3];
        float vv[16] = {v0.x, v0.y, v0.z, v0.w, v1.x, v1.y, v1.z, v1.w,
                        v2.x, v2.y, v2.z, v2.w, v3.x, v3.y, v3.z, v3.w};
        float dd = 0.f;
        unsigned hp[8];
        #pragma unroll
        for (int j = 0; j < 8; j++) {
            float a = vv[2 * j], b = vv[2 * j + 1];
            dd = fmaf(a, a, fmaf(b, b, dd));
            hp[j] = (unsigned)f2bf(a) | ((unsigned)f2bf(b) << 16);
        }
        uint4* dst = (uint4*)(sh_hi + p * 16);
        dst[0] = make_uint4(hp[0], hp[1], hp[2], hp[3]);
        dst[1] = make_uint4(hp[4], hp[5], hp[6], hp[7]);
        float wn = w[n0 + p];
        wsl += wn;
        sh_cn[p] = fmaf(-0.5f * LOG2E, dd, __builtin_amdgcn_logf(wn));
    }
    #pragma unroll
    for (int off = 32; off > 0; off >>= 1) wsl += __shfl_down(wsl, off, 64);
    if (lane == 0) ls[wave] = wsl;

    // ---- A fragments: bf16(L*x) in quads 0,1; zeros in quads 2,3 (K padding)
    bf16x8 afrag[WQT];
    #pragma unroll
    for (int t = 0; t < WQT; t++) {
        int q = (qg * WQT + t) * 16 + col;
        const float* xp = X + (size_t)q * D + koff;
        bf16x8 a;
        #pragma unroll
        for (int j = 0; j < 8; j++)
            a[j] = (quad < 2) ? (short)f2bf(xp[j] * LOG2E) : (short)0;
        afrag[t] = a;
    }

    f32x4 dens[WQT];
    #pragma unroll
    for (int t = 0; t < WQT; t++) dens[t] = (f32x4){0.f, 0.f, 0.f, 0.f};

    __syncthreads();

    if (tid == 0)
        wpart[chunk] = (ls[0] + ls[1]) + (ls[2] + ls[3]);

    // ---- main loop: depth-1 LDS prefetch, 4 independent MFMA->exp2 chains
    const int eoff = (col << 4) + koff;          // shorts
    bf16x8 b1 = *(const bf16x8*)(sh_hi + eoff);
    float  c0 = sh_cn[col];
    for (int it = 0; it < cntt; it++) {
        bf16x8 nb1 = *(const bf16x8*)(sh_hi + (it + 1) * 256 + eoff);
        float  nc0 = sh_cn[(it + 1) * 16 + col];
        f32x4 cvec = {c0, c0, c0, c0};
        #pragma unroll
        for (int t = 0; t < WQT; t++) {
            f32x4 s = __builtin_amdgcn_mfma_f32_16x16x32_bf16(afrag[t], b1, cvec, 0, 0, 0);
            f32x4 e;
            #pragma unroll
            for (int r = 0; r < 4; r++)
                e[r] = __builtin_amdgcn_exp2f(s[r]);
            dens[t] += e;                        // packed f32 adds
        }
        b1 = nb1; c0 = nc0;
    }

    // ---- reduce over the 16 n-lanes, plain store (no atomics)
    #pragma unroll
    for (int t = 0; t < WQT; t++) {
        #pragma unroll
        for (int r = 0; r < 4; r++) {
            float v = dens[t][r];
            v += __shfl_xor(v, 1, 64);
            v += __shfl_xor(v, 2, 64);
            v += __shfl_xor(v, 4, 64);
            v += __shfl_xor(v, 8, 64);
            if (col == 0) {
                int q = (qg * WQT + t) * 16 + quad * 4 + r;
                part[(size_t)chunk * Q + q] = v;
            }
        }
    }

    // ---- completion handshake: last y-block of this column finalizes it
    __syncthreads();                 // all stores issued block-wide
    if (tid == 0) {
        __threadfence();             // release our part/wpart stores (agent scope)
        unsigned prev = __hip_atomic_fetch_add(&cnt[g], 1u, __ATOMIC_ACQ_REL,
                                               __HIP_MEMORY_SCOPE_AGENT);
        amLast = (prev == NCHUNK - 1);
    }
    __syncthreads();
    if (!amLast) return;
    __threadfence();                 // acquire side, belt-and-suspenders

    // ---- finalize 256 queries of this column
    if (tid < 64) {
        float wv = (wpart[tid] + wpart[tid + 64]) + (wpart[tid + 128] + wpart[tid + 192]);
        #pragma unroll
        for (int off = 32; off > 0; off >>= 1) wv += __shfl_down(wv, off, 64);
        if (tid == 0) swsum = wv;
    }
    __syncthreads();

    const int qq = g * 256 + tid;
    float a8[8];
    #pragma unroll
    for (int u = 0; u < 8; u++) a8[u] = 0.f;
    for (int c = 0; c < NCHUNK; c += 8) {
        #pragma unroll
        for (int u = 0; u < 8; u++)
            a8[u] += part[(size_t)(c + u) * Q + qq];
    }
    float dsum = ((a8[0] + a8[1]) + (a8[2] + a8[3]))
               + ((a8[4] + a8[5]) + (a8[6] + a8[7]));

    const float4* xp = (const float4*)(X + (size_t)qq * D);
    float4 x0 = xp[0], x1 = xp[1], x2 = xp[2], x3 = xp[3];
    float xx = x0.x*x0.x + x0.y*x0.y + x0.z*x0.z + x0.w*x0.w
             + x1.x*x1.x + x1.y*x1.y + x1.z*x1.z + x1.w*x1.w
             + x2.x*x2.x + x2.y*x2.y + x2.z*x2.z + x2.w*x2.w
             + x3.x*x3.x + x3.y*x3.y + x3.z*x3.z + x3.w*x3.w;
    float aq = -0.5f * LOG2E * xx;
    const float ln_norm = -8.f * 1.8378770664093453f;  // ln((2*pi)^-8)
    out[qq] = LN2 * (aq + __builtin_amdgcn_logf(dsum)
                        - __builtin_amdgcn_logf(swsum)) + ln_norm;
}

extern "C" void kernel_launch(void* const* d_in, const int* in_sizes, int n_in,
                              void* d_out, int out_size, void* d_ws, size_t ws_size,
                              hipStream_t stream) {
    const float* X    = (const float*)d_in[0];
    const float* data = (const float*)d_in[1];
    const float* w    = (const float*)d_in[2];
    float* out = (float*)d_out;
    int Q = in_sizes[0] / D;   // 2048
    int N = in_sizes[1] / D;   // 100000

    // ws layout: [0..8) u32 counters, [8..8+NCHUNK) wpart, then part (NCHUNK*Q f32)
    unsigned* cnt  = (unsigned*)d_ws;
    float* wpart   = (float*)d_ws + 8;
    float* part    = wpart + NCHUNK;

    hipMemsetAsync(cnt, 0, 8 * sizeof(unsigned), stream);   // counters only

    dim3 grid(Q / (4 * WQT * 16), NCHUNK);   // (8, 256)
    dens_kernel<<<grid, 256, 0, stream>>>(X, data, w, part, wpart, cnt, out, Q, N);
}

// Round 10
// 106.034 us; speedup vs baseline: 2.0106x; 2.0106x over previous
//
#include <hip/hip_runtime.h>

#define D 16
#define WQT 4        // q-tiles (of 16 queries) per wave -> 64 queries/wave
#define NCHUNK 192   // n-dimension grid split (R6-measured best: dens 46.9 us)
#define TILES_MAX 33 // base=32 (+1 for the first `rem` chunks)
#define FIN_QPB 64   // queries per fin block (x 3 segments = 192 threads)

#define LOG2E 1.4426950408889634f
#define LN2   0.6931471805599453f

typedef __attribute__((ext_vector_type(8))) short bf16x8;
typedef __attribute__((ext_vector_type(4))) float f32x4;

__device__ __forceinline__ unsigned short f2bf(float f) {
    unsigned u = __float_as_uint(f);
    unsigned r = (u + 0x7fffu + ((u >> 16) & 1u)) >> 16;
    return (unsigned short)r;
}

// ---------------- fused convert + weight-sum + density partials via MFMA ----------
// part[chunk][q] = sum_{n in chunk} exp2( L*(x_q.d_n) - 0.5*L*|d_n|^2 + log2 w_n )
// wpart[chunk]   = sum_{n in chunk} w_n  (idempotent: all 8 x-blocks write same value)
__global__ __launch_bounds__(256, 6) void dens_kernel(
        const float* __restrict__ X, const float* __restrict__ data,
        const float* __restrict__ w, float* __restrict__ part,
        float* __restrict__ wpart, int Q, int N) {
    // +1 tile pad so the depth-1 prefetch can read one-past-end harmlessly
    __shared__ unsigned short sh_hi[(TILES_MAX + 1) * 256];  // 17.4 KB
    __shared__ float          sh_cn[(TILES_MAX + 1) * 16];   // 2.2 KB
    __shared__ float          ls[4];

    const int lane = threadIdx.x & 63;
    const int wave = threadIdx.x >> 6;
    const int col  = lane & 15;        // A: m-index; C/D: n-index
    const int quad = lane >> 4;
    const int koff = (quad & 1) * 8;   // k-slice within D=16

    const int qg = blockIdx.x * 4 + wave;   // 64 queries per wave

    // ---- this block's n-tile range (tiles of 16 points)
    const int NT = N >> 4;                       // 6250
    const int base = NT / NCHUNK, rem = NT % NCHUNK;
    const int chunk = blockIdx.y;
    const int tile0 = chunk * base + min(chunk, rem);
    const int cnt = base + (chunk < rem ? 1 : 0);
    const int npts = cnt * 16;
    const int n0 = tile0 * 16;

    // ---- stage: fp32 -> bf16 pack + per-point constant into LDS; weight sum aside
    float ws = 0.f;
    for (int p = threadIdx.x; p < npts; p += 256) {
        const float4* dp = (const float4*)(data + (size_t)(n0 + p) * D);
        float4 v0 = dp[0], v1 = dp[1], v2 = dp[2], v3 = dp[3];
        float vv[16] = {v0.x, v0.y, v0.z, v0.w, v1.x, v1.y, v1.z, v1.w,
                        v2.x, v2.y, v2.z, v2.w, v3.x, v3.y, v3.z, v3.w};
        float dd = 0.f;
        unsigned hp[8];
        #pragma unroll
        for (int j = 0; j < 8; j++) {
            float a = vv[2 * j], b = vv[2 * j + 1];
            dd = fmaf(a, a, fmaf(b, b, dd));
            hp[j] = (unsigned)f2bf(a) | ((unsigned)f2bf(b) << 16);
        }
        uint4* dst = (uint4*)(sh_hi + p * 16);
        dst[0] = make_uint4(hp[0], hp[1], hp[2], hp[3]);
        dst[1] = make_uint4(hp[4], hp[5], hp[6], hp[7]);
        float wn = w[n0 + p];
        ws += wn;
        sh_cn[p] = fmaf(-0.5f * LOG2E, dd, __builtin_amdgcn_logf(wn));
    }
    #pragma unroll
    for (int off = 32; off > 0; off >>= 1) ws += __shfl_down(ws, off, 64);
    if (lane == 0) ls[wave] = ws;

    // ---- A fragments: bf16(L*x) in quads 0,1; zeros in quads 2,3 (K padding)
    bf16x8 afrag[WQT];
    #pragma unroll
    for (int t = 0; t < WQT; t++) {
        int q = (qg * WQT + t) * 16 + col;
        const float* xp = X + (size_t)q * D + koff;
        bf16x8 a;
        #pragma unroll
        for (int j = 0; j < 8; j++)
            a[j] = (quad < 2) ? (short)f2bf(xp[j] * LOG2E) : (short)0;
        afrag[t] = a;
    }

    f32x4 dens[WQT];
    #pragma unroll
    for (int t = 0; t < WQT; t++) dens[t] = (f32x4){0.f, 0.f, 0.f, 0.f};

    __syncthreads();

    if (threadIdx.x == 0)
        wpart[chunk] = (ls[0] + ls[1]) + (ls[2] + ls[3]);

    // ---- main loop: depth-1 LDS prefetch, 4 independent MFMA->exp2 chains
    const int eoff = (col << 4) + koff;          // shorts
    bf16x8 b1 = *(const bf16x8*)(sh_hi + eoff);
    float  c0 = sh_cn[col];
    for (int it = 0; it < cnt; it++) {
        bf16x8 nb1 = *(const bf16x8*)(sh_hi + (it + 1) * 256 + eoff);
        float  nc0 = sh_cn[(it + 1) * 16 + col];
        f32x4 cvec = {c0, c0, c0, c0};
        #pragma unroll
        for (int t = 0; t < WQT; t++) {
            f32x4 s = __builtin_amdgcn_mfma_f32_16x16x32_bf16(afrag[t], b1, cvec, 0, 0, 0);
            f32x4 e;
            #pragma unroll
            for (int r = 0; r < 4; r++)
                e[r] = __builtin_amdgcn_exp2f(s[r]);
            dens[t] += e;                        // packed f32 adds
        }
        b1 = nb1; c0 = nc0;
    }

    // ---- reduce over the 16 n-lanes, plain store (no atomics)
    #pragma unroll
    for (int t = 0; t < WQT; t++) {
        #pragma unroll
        for (int r = 0; r < 4; r++) {
            float v = dens[t][r];
            v += __shfl_xor(v, 1, 64);
            v += __shfl_xor(v, 2, 64);
            v += __shfl_xor(v, 4, 64);
            v += __shfl_xor(v, 8, 64);
            if (col == 0) {
                int q = (qg * WQT + t) * 16 + quad * 4 + r;
                part[(size_t)chunk * Q + q] = v;
            }
        }
    }
}

// ---------------- finalize: parallel chunk reduce + wave-parallel wsum + log ------
// 32 blocks x 192 threads; each block covers 64 queries, 3 threads per query
// (each summing 64 chunks, coalesced), LDS combine, then 64 threads finalize.
__global__ __launch_bounds__(192) void fin_kernel(
        const float* __restrict__ X, const float* __restrict__ part,
        const float* __restrict__ wpart, float* __restrict__ out, int Q) {
    __shared__ float sred[3][FIN_QPB];
    __shared__ float swsum;

    const int tid = threadIdx.x;
    const int qi = tid & (FIN_QPB - 1);
    const int seg = tid >> 6;              // which 64-chunk segment (0..2)
    const int q = blockIdx.x * FIN_QPB + qi;

    // partial sum over this segment's 64 chunks (coalesced across qi lanes)
    float a0 = 0.f, a1 = 0.f, a2 = 0.f, a3 = 0.f;
    const int c0 = seg * 64;
    #pragma unroll 4
    for (int c = 0; c < 64; c += 4) {
        a0 += part[(size_t)(c0 + c + 0) * Q + q];
        a1 += part[(size_t)(c0 + c + 1) * Q + q];
        a2 += part[(size_t)(c0 + c + 2) * Q + q];
        a3 += part[(size_t)(c0 + c + 3) * Q + q];
    }
    sred[seg][qi] = (a0 + a1) + (a2 + a3);

    // wave 0: wsum via 3 loads/lane + shuffle reduce (192 chunks)
    if (tid < 64) {
        float wv = wpart[tid] + wpart[tid + 64] + wpart[tid + 128];
        #pragma unroll
        for (int off = 32; off > 0; off >>= 1) wv += __shfl_down(wv, off, 64);
        if (tid == 0) swsum = wv;
    }
    __syncthreads();

    if (tid < FIN_QPB) {
        float dsum = sred[0][tid] + sred[1][tid] + sred[2][tid];
        int qq = blockIdx.x * FIN_QPB + tid;
        const float4* xp = (const float4*)(X + (size_t)qq * D);
        float4 x0 = xp[0], x1 = xp[1], x2 = xp[2], x3 = xp[3];
        float xx = x0.x*x0.x + x0.y*x0.y + x0.z*x0.z + x0.w*x0.w
                 + x1.x*x1.x + x1.y*x1.y + x1.z*x1.z + x1.w*x1.w
                 + x2.x*x2.x + x2.y*x2.y + x2.z*x2.z + x2.w*x2.w
                 + x3.x*x3.x + x3.y*x3.y + x3.z*x3.z + x3.w*x3.w;
        float aq = -0.5f * LOG2E * xx;
        const float ln_norm = -8.f * 1.8378770664093453f;  // ln((2*pi)^-8)
        out[qq] = LN2 * (aq + __builtin_amdgcn_logf(dsum)
                            - __builtin_amdgcn_logf(swsum)) + ln_norm;
    }
}

extern "C" void kernel_launch(void* const* d_in, const int* in_sizes, int n_in,
                              void* d_out, int out_size, void* d_ws, size_t ws_size,
                              hipStream_t stream) {
    const float* X    = (const float*)d_in[0];
    const float* data = (const float*)d_in[1];
    const float* w    = (const float*)d_in[2];
    float* out = (float*)d_out;
    int Q = in_sizes[0] / D;   // 2048
    int N = in_sizes[1] / D;   // 100000

    // ws layout (floats): [0..NCHUNK) wpart, then part (NCHUNK*Q floats).
    // Everything written before read each launch -> no memset needed.
    float* wpart = (float*)d_ws;
    float* part  = wpart + NCHUNK;

    dim3 grid(Q / (4 * WQT * 16), NCHUNK);   // (8, 192)
    dens_kernel<<<grid, 256, 0, stream>>>(X, data, w, part, wpart, Q, N);

    fin_kernel<<<Q / FIN_QPB, 192, 0, stream>>>(X, part, wpart, out, Q);
}